// Round 1
// baseline (259.281 us; speedup 1.0000x reference)
//
#include <hip/hip_runtime.h>

#define B_ 4
#define T_ 2048
#define D_ 1024
#define H_ 16
#define DH_ 64
#define BH_ (B_*H_)   // 64
#define M_ (B_*T_)    // 8192
#define N3_ (3*D_)    // 3072

typedef __attribute__((ext_vector_type(8))) __bf16 bf16x8;
typedef __attribute__((ext_vector_type(4))) float f32x4;
typedef __attribute__((ext_vector_type(8))) unsigned short u16x8;

__device__ inline void gload_lds16(const void* g, void* l) {
  __builtin_amdgcn_global_load_lds((const __attribute__((address_space(1))) void*)g,
                                   (__attribute__((address_space(3))) void*)l, 16, 0, 0);
}

__device__ inline unsigned short f2bf(float v) {
  __bf16 t = (__bf16)v;
  return *(unsigned short*)&t;
}

// ---------------- cast x: f32 -> bf16, 8 elems/thread ----------------
__global__ void cast_f32_bf16(const float* __restrict__ in, unsigned short* __restrict__ out, int n8) {
  int i = blockIdx.x * blockDim.x + threadIdx.x;
  if (i >= n8) return;
  const float4* p = (const float4*)(in + (size_t)i * 8);
  float4 a = p[0], b = p[1];
  float v[8] = {a.x, a.y, a.z, a.w, b.x, b.y, b.z, b.w};
  u16x8 r;
#pragma unroll
  for (int j = 0; j < 8; ++j) r[j] = f2bf(v[j]);
  *(u16x8*)(out + (size_t)i * 8) = r;
}

// ------------- transpose+cast weights: f32 [K][N] -> bf16 [N][K] -------------
__global__ void transpose_cast_w(const float* __restrict__ w, unsigned short* __restrict__ wt,
                                 int Kdim, int Ndim) {
  __shared__ unsigned short lds[64][72];
  int n0 = blockIdx.x * 64, k0 = blockIdx.y * 64;
  int tid = threadIdx.x;
#pragma unroll
  for (int i = 0; i < 2; ++i) {
    int idx = i * 256 + tid;
    int r = idx >> 3, c8 = idx & 7;
    const float4* src = (const float4*)(w + (size_t)(k0 + r) * Ndim + n0 + c8 * 8);
    float4 a = src[0], b = src[1];
    float v[8] = {a.x, a.y, a.z, a.w, b.x, b.y, b.z, b.w};
#pragma unroll
    for (int j = 0; j < 8; ++j) lds[r][c8 * 8 + j] = f2bf(v[j]);
  }
  __syncthreads();
#pragma unroll
  for (int i = 0; i < 2; ++i) {
    int idx = i * 256 + tid;
    int r = idx >> 3, c8 = idx & 7;   // r = n-local out row, c8 = k chunk
    u16x8 o;
#pragma unroll
    for (int j = 0; j < 8; ++j) o[j] = lds[c8 * 8 + j][r];
    *(u16x8*)(wt + (size_t)(n0 + r) * Kdim + k0 + c8 * 8) = o;
  }
}

// ------------- transpose V: bf16 [bh][T][64] -> [bh][64][T] -------------
__global__ void transpose_v(const unsigned short* __restrict__ v, unsigned short* __restrict__ vt) {
  __shared__ unsigned short lds[64][72];
  int t0 = blockIdx.x * 64;
  int bh = blockIdx.y;
  int tid = threadIdx.x;
#pragma unroll
  for (int i = 0; i < 2; ++i) {
    int idx = i * 256 + tid;
    int r = idx >> 3, c8 = idx & 7;
    u16x8 a = *(const u16x8*)(v + ((size_t)bh * T_ + t0 + r) * 64 + c8 * 8);
#pragma unroll
    for (int j = 0; j < 8; ++j) lds[r][c8 * 8 + j] = a[j];
  }
  __syncthreads();
#pragma unroll
  for (int i = 0; i < 2; ++i) {
    int idx = i * 256 + tid;
    int d = idx >> 3, c8 = idx & 7;
    u16x8 o;
#pragma unroll
    for (int j = 0; j < 8; ++j) o[j] = lds[c8 * 8 + j][d];
    *(u16x8*)(vt + ((size_t)bh * 64 + d) * T_ + t0 + c8 * 8) = o;
  }
}

// ------------- GEMM: C[M][N] = A[M][1024] * BT[N][1024]^T (bf16 in, fp32 acc) -------------
// epi 0: scatter to q/k/v bufs (bf16, q scaled 0.125); epi 1: fp32 out
__global__ __launch_bounds__(256) void gemm_bt(
    const unsigned short* __restrict__ A,
    const unsigned short* __restrict__ BT,
    int epi,
    unsigned short* __restrict__ qb, unsigned short* __restrict__ kb, unsigned short* __restrict__ vb,
    float* __restrict__ outf) {
  __shared__ __align__(16) unsigned short sA[128 * 64];
  __shared__ __align__(16) unsigned short sB[128 * 64];
  const int tid = threadIdx.x;
  const int wave = tid >> 6, lane = tid & 63, g = lane >> 4, c = lane & 15;
  const int wm = wave >> 1, wn = wave & 1;
  const int m0 = blockIdx.x * 128, n0 = blockIdx.y * 128;

  f32x4 acc[4][4] = {};

  for (int ks = 0; ks < 16; ++ks) {
    const int k0 = ks * 64;
#pragma unroll
    for (int i = 0; i < 4; ++i) {
      int idx = i * 256 + tid;
      int r = idx >> 3, s = idx & 7;
      gload_lds16(A + (size_t)(m0 + r) * 1024 + k0 + 8 * (s ^ (r & 7)),
                  (char*)sA + (i * 256 + wave * 64) * 16);
    }
#pragma unroll
    for (int i = 0; i < 4; ++i) {
      int idx = i * 256 + tid;
      int r = idx >> 3, s = idx & 7;
      gload_lds16(BT + (size_t)(n0 + r) * 1024 + k0 + 8 * (s ^ (r & 7)),
                  (char*)sB + (i * 256 + wave * 64) * 16);
    }
    __syncthreads();
#pragma unroll
    for (int kc = 0; kc < 2; ++kc) {
      bf16x8 af[4], bf[4];
#pragma unroll
      for (int mt = 0; mt < 4; ++mt) {
        int r = wm * 64 + mt * 16 + c;
        af[mt] = *(const bf16x8*)((const char*)sA + r * 128 + 16 * ((4 * kc + g) ^ (r & 7)));
      }
#pragma unroll
      for (int nt = 0; nt < 4; ++nt) {
        int r = wn * 64 + nt * 16 + c;
        bf[nt] = *(const bf16x8*)((const char*)sB + r * 128 + 16 * ((4 * kc + g) ^ (r & 7)));
      }
#pragma unroll
      for (int mt = 0; mt < 4; ++mt)
#pragma unroll
        for (int nt = 0; nt < 4; ++nt)
          acc[mt][nt] = __builtin_amdgcn_mfma_f32_16x16x32_bf16(af[mt], bf[nt], acc[mt][nt], 0, 0, 0);
    }
    __syncthreads();
  }

  if (epi == 0) {
    int which = n0 >> 10;  // 0:q 1:k 2:v  (BN=128 divides 1024, so uniform per block)
    int colbase = n0 - (which << 10);
    unsigned short* dst = which == 0 ? qb : (which == 1 ? kb : vb);
    float scale = which == 0 ? 0.125f : 1.0f;  // 1/sqrt(64), exact in bf16
#pragma unroll
    for (int mt = 0; mt < 4; ++mt)
#pragma unroll
      for (int nt = 0; nt < 4; ++nt)
#pragma unroll
        for (int i = 0; i < 4; ++i) {
          int m = m0 + wm * 64 + mt * 16 + g * 4 + i;
          int n = colbase + wn * 64 + nt * 16 + c;
          int b = m >> 11, t = m & 2047;
          int h = n >> 6, d = n & 63;
          dst[(((size_t)(b * H_ + h) * T_ + t) << 6) + d] = f2bf(acc[mt][nt][i] * scale);
        }
  } else {
#pragma unroll
    for (int mt = 0; mt < 4; ++mt)
#pragma unroll
      for (int nt = 0; nt < 4; ++nt)
#pragma unroll
        for (int i = 0; i < 4; ++i) {
          int m = m0 + wm * 64 + mt * 16 + g * 4 + i;
          int n = n0 + wn * 64 + nt * 16 + c;
          outf[(size_t)m * 1024 + n] = acc[mt][nt][i];
        }
  }
}

// ------------- flash attention: 1 block = (bh, 64 q rows), 4 waves x 16 q rows -------------
__global__ __launch_bounds__(256) void attn(
    const unsigned short* __restrict__ qb,  // [bh][T][64], pre-scaled by 0.125
    const unsigned short* __restrict__ kb,  // [bh][T][64]
    const unsigned short* __restrict__ vt,  // [bh][64][T]
    unsigned short* __restrict__ ao) {      // [M][1024] bf16
  __shared__ __align__(16) unsigned short sK[64 * 64];
  __shared__ __align__(16) unsigned short sV[64 * 64];   // holds V^T tile: [d][k]
  __shared__ __align__(16) unsigned short sP[4 * 16 * 72];
  const int tid = threadIdx.x;
  const int wave = tid >> 6, lane = tid & 63, g = lane >> 4, c = lane & 15;
  const int qt = blockIdx.x, bh = blockIdx.y;
  const int q0 = qt * 64 + wave * 16;  // this wave's q strip

  // Q as B-fragments (lane holds Q[q0+c][kc*32 + g*8 + j])
  bf16x8 qf[2];
#pragma unroll
  for (int kc = 0; kc < 2; ++kc)
    qf[kc] = *(const bf16x8*)(qb + ((size_t)bh * T_ + q0 + c) * 64 + kc * 32 + g * 8);

  float m_run = -INFINITY, l_run = 0.0f;
  f32x4 o[4] = {};
  unsigned short* sPw = sP + wave * 16 * 72;

  for (int kt = 0; kt <= qt; ++kt) {
    __syncthreads();  // protect sK/sV from previous iteration readers
#pragma unroll
    for (int i = 0; i < 2; ++i) {
      int idx = i * 256 + tid;
      int r = idx >> 3, s = idx & 7;
      gload_lds16(kb + ((size_t)bh * T_ + kt * 64 + r) * 64 + 8 * (s ^ (r & 7)),
                  (char*)sK + (i * 256 + wave * 64) * 16);
      gload_lds16(vt + ((size_t)bh * 64 + r) * T_ + kt * 64 + 8 * (s ^ (r & 7)),
                  (char*)sV + (i * 256 + wave * 64) * 16);
    }
    __syncthreads();

    // S^T = K * Q^T : lane holds S[k = 16*mt + 4*g + i][q = c]
    f32x4 st[4] = {};
#pragma unroll
    for (int kc = 0; kc < 2; ++kc)
#pragma unroll
      for (int mt = 0; mt < 4; ++mt) {
        int r = mt * 16 + c;
        bf16x8 kf = *(const bf16x8*)((const char*)sK + r * 128 + 16 * ((4 * kc + g) ^ (r & 7)));
        st[mt] = __builtin_amdgcn_mfma_f32_16x16x32_bf16(kf, qf[kc], st[mt], 0, 0, 0);
      }

    if (kt == qt) {  // causal mask, diagonal tile only
      int qg = q0 + c;
#pragma unroll
      for (int mt = 0; mt < 4; ++mt)
#pragma unroll
        for (int i = 0; i < 4; ++i) {
          int kg = kt * 64 + mt * 16 + g * 4 + i;
          if (kg > qg) st[mt][i] = -INFINITY;
        }
    }

    // online softmax for row q = c (4 g-lanes hold disjoint k slices)
    float mx = -INFINITY;
#pragma unroll
    for (int mt = 0; mt < 4; ++mt)
#pragma unroll
      for (int i = 0; i < 4; ++i) mx = fmaxf(mx, st[mt][i]);
    mx = fmaxf(mx, __shfl_xor(mx, 16));
    mx = fmaxf(mx, __shfl_xor(mx, 32));
    float m_new = fmaxf(m_run, mx);
    float al = __expf(m_run - m_new);
    float ps = 0.0f;
#pragma unroll
    for (int mt = 0; mt < 4; ++mt)
#pragma unroll
      for (int i = 0; i < 4; ++i) {
        float p = __expf(st[mt][i] - m_new);
        st[mt][i] = p;
        ps += p;
      }
    ps += __shfl_xor(ps, 16);
    ps += __shfl_xor(ps, 32);
    l_run = l_run * al + ps;
    m_run = m_new;

    // P -> per-wave LDS at [q=c][k]
#pragma unroll
    for (int mt = 0; mt < 4; ++mt)
#pragma unroll
      for (int i = 0; i < 4; ++i)
        sPw[c * 72 + mt * 16 + g * 4 + i] = f2bf(st[mt][i]);

    // rescale O (O rows are q = 4g + i; al lives at lanes with (lane&15) == q)
    float alr[4];
#pragma unroll
    for (int i = 0; i < 4; ++i) alr[i] = __shfl(al, g * 16 + g * 4 + i);
#pragma unroll
    for (int nt = 0; nt < 4; ++nt)
#pragma unroll
      for (int i = 0; i < 4; ++i) o[nt][i] *= alr[i];

    // O += P * V  (A = P from LDS, B = V^T rows from sV)
#pragma unroll
    for (int kc = 0; kc < 2; ++kc) {
      bf16x8 pf = *(const bf16x8*)((const char*)sPw + c * 144 + kc * 64 + g * 16);
#pragma unroll
      for (int nt = 0; nt < 4; ++nt) {
        int r = nt * 16 + c;
        bf16x8 vf = *(const bf16x8*)((const char*)sV + r * 128 + 16 * ((4 * kc + g) ^ (r & 7)));
        o[nt] = __builtin_amdgcn_mfma_f32_16x16x32_bf16(pf, vf, o[nt], 0, 0, 0);
      }
    }
  }

  // finalize: divide by l, store bf16 to [b][t][h*64+d]
  float lr[4];
#pragma unroll
  for (int i = 0; i < 4; ++i) lr[i] = __shfl(l_run, g * 16 + g * 4 + i);
  int b = bh >> 4, h = bh & 15;
#pragma unroll
  for (int nt = 0; nt < 4; ++nt)
#pragma unroll
    for (int i = 0; i < 4; ++i) {
      int t = q0 + g * 4 + i;
      int dcol = h * 64 + nt * 16 + c;
      ao[((size_t)(b * T_ + t)) * 1024 + dcol] = f2bf(o[nt][i] / lr[i]);
    }
}

extern "C" void kernel_launch(void* const* d_in, const int* in_sizes, int n_in,
                              void* d_out, int out_size, void* d_ws, size_t ws_size,
                              hipStream_t stream) {
  const float* x = (const float*)d_in[0];
  const float* w_qkv = (const float*)d_in[1];
  const float* w_out = (const float*)d_in[2];
  float* out = (float*)d_out;

  char* ws = (char*)d_ws;
  size_t off = 0;
  auto alloc = [&](size_t bytes) {
    char* p = ws + off;
    off += (bytes + 255) & ~(size_t)255;
    return p;
  };
  unsigned short* xb    = (unsigned short*)alloc((size_t)M_ * D_ * 2);
  unsigned short* wqkvT = (unsigned short*)alloc((size_t)N3_ * D_ * 2);
  unsigned short* woutT = (unsigned short*)alloc((size_t)D_ * D_ * 2);
  unsigned short* qbuf  = (unsigned short*)alloc((size_t)BH_ * T_ * 64 * 2);
  unsigned short* kbuf  = (unsigned short*)alloc((size_t)BH_ * T_ * 64 * 2);
  unsigned short* vbuf  = (unsigned short*)alloc((size_t)BH_ * T_ * 64 * 2);
  unsigned short* vtb   = (unsigned short*)alloc((size_t)BH_ * 64 * T_ * 2);
  unsigned short* ao    = xb;  // reuse: xb dead after QKV GEMM

  cast_f32_bf16<<<(M_ * D_ / 8 + 255) / 256, 256, 0, stream>>>(x, xb, M_ * D_ / 8);
  transpose_cast_w<<<dim3(N3_ / 64, D_ / 64), 256, 0, stream>>>(w_qkv, wqkvT, D_, N3_);
  transpose_cast_w<<<dim3(D_ / 64, D_ / 64), 256, 0, stream>>>(w_out, woutT, D_, D_);
  gemm_bt<<<dim3(M_ / 128, N3_ / 128), 256, 0, stream>>>(xb, wqkvT, 0, qbuf, kbuf, vbuf, nullptr);
  transpose_v<<<dim3(T_ / 64, BH_), 256, 0, stream>>>(vbuf, vtb);
  attn<<<dim3(T_ / 64, BH_), 256, 0, stream>>>(qbuf, kbuf, vtb, ao);
  gemm_bt<<<dim3(M_ / 128, D_ / 128), 256, 0, stream>>>(ao, woutT, 1, nullptr, nullptr, nullptr, out);
}